// Round 11
// baseline (4233.535 us; speedup 1.0000x reference)
//
#include <hip/hip_runtime.h>

// Sizes (fixed): V=512, F_IN=8, H=64, DH=4, T=3, E=8192, P=64, L=8, D=68

__device__ __forceinline__ float fsig_(float x) { return 1.f / (1.f + __expf(-x)); }
__device__ __forceinline__ float ftanh_(float x) {
  float e = __expf(2.f * x);
  return 1.f - 2.f / (e + 1.f);
}
__device__ __forceinline__ float sig_(float x) { return 1.f / (1.f + expf(-x)); }

// Barrier WITHOUT vmcnt drain: LDS ordering only.
__device__ __forceinline__ void barrier_lgkm() {
  asm volatile("s_waitcnt lgkmcnt(0)\n\ts_barrier" ::: "memory");
}

// Pin a float4 into VGPRs (opaque redefinition, blocks rematerialization).
#define PIN4(v) asm volatile("" : "+v"((v).x), "+v"((v).y), "+v"((v).z), "+v"((v).w))

// async global->LDS, 4 bytes/lane: LDS dst = uniform base + lane*4.
#define GLD_LDS4(gp, lp)                                                       \
  __builtin_amdgcn_global_load_lds(                                            \
      (const __attribute__((address_space(1))) void*)(gp),                     \
      (__attribute__((address_space(3))) void*)(lp), 4, 0, 0)

// NOTE: macro params must NOT collide with float4 member names (x/y/z/w).
#define LD4(p) (*(const float4*)(p))
#define DOT4(acc, va, vb)                                                      \
  do {                                                                         \
    acc += (va).x * (vb).x; acc += (va).y * (vb).y;                            \
    acc += (va).z * (vb).z; acc += (va).w * (vb).w;                            \
  } while (0)

#define ALL16(M) M(0) M(1) M(2) M(3) M(4) M(5) M(6) M(7)                       \
                 M(8) M(9) M(10) M(11) M(12) M(13) M(14) M(15)
#define ALLQ(M) M(0,0) M(1,1) M(2,2) M(3,3) M(4,0) M(5,1) M(6,2) M(7,3)        \
                M(8,0) M(9,1) M(10,2) M(11,3) M(12,0) M(13,1) M(14,2) M(15,3)

// x[i,j,h] = sum_f adj[i,j,f] * emb[h,f]
__global__ __launch_bounds__(256) void embed_kernel(
    const float* __restrict__ adj, const float* __restrict__ emb,
    float* __restrict__ x)
{
  const int64_t row = (int64_t)blockIdx.x * 4 + (threadIdx.x >> 6);
  const int h = threadIdx.x & 63;
  const float* a = adj + row * 8;
  float acc = 0.f;
#pragma unroll
  for (int f = 0; f < 8; ++f) acc += a[f] * emb[h * 8 + f];
  x[row * 64 + h] = acc;
}

// col_sum[j,h] = sum_i x[i,j,h];  col_nz[j] = sum_i sum_h (x[i,j,h]!=0)
__global__ __launch_bounds__(256) void colsum_kernel(
    const float* __restrict__ x, float* __restrict__ col_sum,
    int* __restrict__ col_nz)
{
  const int j = blockIdx.x;
  const int h = threadIdx.x & 63;
  const int w = threadIdx.x >> 6;
  float acc = 0.f;
  int nz = 0;
  for (int i = w; i < 512; i += 4) {
    float v = x[((int64_t)i * 512 + j) * 64 + h];
    acc += v;
    nz += (v != 0.f) ? 1 : 0;
  }
  __shared__ float pacc[4][64];
  __shared__ int pnz[4];
#pragma unroll
  for (int off = 32; off > 0; off >>= 1) nz += __shfl_down(nz, off, 64);
  if (h == 0) pnz[w] = nz;
  pacc[w][h] = acc;
  __syncthreads();
  if (w == 0) {
    col_sum[j * 64 + h] = pacc[0][h] + pacc[1][h] + pacc[2][h] + pacc[3][h];
    if (h == 0) col_nz[j] = pnz[0] + pnz[1] + pnz[2] + pnz[3];
  }
}

__global__ void scatter_idx_kernel(const int* __restrict__ edges,
                                   int* __restrict__ idxmap)
{
  const int e = blockIdx.x * 256 + threadIdx.x;
  if (e < 8192) idxmap[edges[e * 2] * 512 + edges[e * 2 + 1]] = e;
}

// Per-edge message m_e, then delta_gi[e,g] = sum_h (m_e[h]-x_uv[h]) * w_ih[g,h]
__global__ __launch_bounds__(64) void edge_kernel(
    const float* __restrict__ x, const int* __restrict__ edges,
    const float* __restrict__ col_sum, const int* __restrict__ col_nz,
    const float* __restrict__ w1, const float* __restrict__ w2,
    const float* __restrict__ w3, const float* __restrict__ w_ih,
    float* __restrict__ delta_gi)
{
  const int e = blockIdx.x;
  const int h = threadIdx.x;
  const int u = edges[e * 2 + 0];
  const int v = edges[e * 2 + 1];
  __shared__ __align__(16) float xuv[64], ein[64], eout[64], dm[64];
  const float xuvh = x[((int64_t)u * 512 + v) * 64 + h];
  const float xvuh = x[((int64_t)v * 512 + u) * 64 + h];
  xuv[h] = xuvh;
  const int nz_vu = __popcll(__ballot(xvuh != 0.f));
  const int nz_uv = __popcll(__ballot(xuvh != 0.f));
  float n_in = (float)(col_nz[u] - nz_vu) / 64.f;
  if (n_in == 0.f) n_in = 1.f;
  float n_out = (float)(col_nz[v] - nz_uv) / 64.f;
  if (n_out == 0.f) n_out = 1.f;
  ein[h] = (col_sum[u * 64 + h] - xvuh) / n_in;
  eout[h] = (col_sum[v * 64 + h] - xuvh) / n_out;
  __syncthreads();
  const float4* w1r = (const float4*)(w1 + h * 64);
  const float4* w2r = (const float4*)(w2 + h * 64);
  const float4* w3r = (const float4*)(w3 + h * 64);
  const float4* xuv4 = (const float4*)xuv;
  const float4* ein4 = (const float4*)ein;
  const float4* eout4 = (const float4*)eout;
  float acc = 0.f;
#pragma unroll
  for (int kk = 0; kk < 16; ++kk) {
    float4 a = xuv4[kk], b = w1r[kk];
    acc += a.x * b.x + a.y * b.y + a.z * b.z + a.w * b.w;
    a = ein4[kk]; b = w2r[kk];
    acc += a.x * b.x + a.y * b.y + a.z * b.z + a.w * b.w;
    a = eout4[kk]; b = w3r[kk];
    acc += a.x * b.x + a.y * b.y + a.z * b.z + a.w * b.w;
  }
  const float m = fmaxf(acc, 0.f);
  dm[h] = m - xuvh;
  __syncthreads();
  const float4* dm4 = (const float4*)dm;
#pragma unroll
  for (int r = 0; r < 3; ++r) {
    const int gg = h + r * 64;
    const float4* wr = (const float4*)(w_ih + gg * 128);
    float d = 0.f;
#pragma unroll
    for (int kk = 0; kk < 16; ++kk) {
      float4 a = dm4[kk], b = wr[kk];
      d += a.x * b.x + a.y * b.y + a.z * b.z + a.w * b.w;
    }
    delta_gi[e * 192 + gg] = d;
  }
}

// ---- GRU scan v7: DMA-wave x-ring + fused gate-waves. ----
// 256 thr = 4 waves, ONE row per block, grid 512 (2 blocks/CU).
// Wave 3 = DMA: per step issues ONE global_load_lds of x[t+8] into a 16-slot
//   LDS ring, then s_waitcnt vmcnt(3) (counted, never 0) -> x[t+4] landed
//   before the barrier. HBM latency absorbed by 8-deep pipeline.
// Waves 0-2 = gate tau (r/z/n), thread owns gate g=tid: whh row g in 16
//   pinned f4 (64 VGPR); x-side gi computed 4 steps at a time from the ring
//   with wsumT[k][g] (transposed in LDS -> conflict-free b32 reads).
//   r,z -> LDS before B1; n-wave finishes h after B1. 2 barriers/step.
#define DECL_WC(i) float4 WC##i = LD4(wc + 4 * (i)); PIN4(WC##i);
#define HQ(i, q) { float4 hc = hs4[(i)]; DOT4(hh##q, hc, WC##i); }

#define GIBATCH(ga, gb, gc, gd, tbase)                                         \
  {                                                                            \
    const int sA = ((tbase) + 1) & 15, sB = ((tbase) + 2) & 15;                \
    const int sC = ((tbase) + 3) & 15, sD = ((tbase) + 4) & 15;                \
    ga = bi; gb = bi; gc = bi; gd = bi;                                        \
    _Pragma("unroll")                                                          \
    for (int q = 0; q < 16; ++q) {                                             \
      const float4 va = *(const float4*)&xring[sA][4 * q];                     \
      const float4 vb = *(const float4*)&xring[sB][4 * q];                     \
      const float4 vc = *(const float4*)&xring[sC][4 * q];                     \
      const float4 vd = *(const float4*)&xring[sD][4 * q];                     \
      const float w0 = wsumT[4 * q + 0][g];                                    \
      const float w1 = wsumT[4 * q + 1][g];                                    \
      const float w2 = wsumT[4 * q + 2][g];                                    \
      const float w3 = wsumT[4 * q + 3][g];                                    \
      ga += va.x * w0 + va.y * w1 + va.z * w2 + va.w * w3;                     \
      gb += vb.x * w0 + vb.y * w1 + vb.z * w2 + vb.w * w3;                     \
      gc += vc.x * w0 + vc.y * w1 + vc.z * w2 + vc.w * w3;                     \
      gd += vd.x * w0 + vd.y * w1 + vd.z * w2 + vd.w * w3;                     \
    }                                                                          \
    { const int i1 = idxl[(tbase) + 1];                                        \
      if (i1 >= 0) ga += delta_gi[(int64_t)i1 * 192 + g];                      \
      const int i2 = idxl[(tbase) + 2];                                        \
      if (i2 >= 0) gb += delta_gi[(int64_t)i2 * 192 + g];                      \
      const int i3 = idxl[(tbase) + 3];                                        \
      if (i3 >= 0) gc += delta_gi[(int64_t)i3 * 192 + g];                      \
      const int i4 = ((tbase) + 4 < 512) ? idxl[(tbase) + 4] : -1;             \
      if (i4 >= 0) gd += delta_gi[(int64_t)i4 * 192 + g]; }                    \
  }

#define HSTEP(gcur, tcur)                                                      \
  {                                                                            \
    float hh0 = bc, hh1 = 0.f, hh2 = 0.f, hh3 = 0.f;                           \
    ALLQ(HQ)                                                                   \
    const float gh = (hh0 + hh1) + (hh2 + hh3);                                \
    if (tau == 0) rzb[0][j] = fsig_((gcur) + gh);                              \
    else if (tau == 1) rzb[1][j] = fsig_((gcur) + gh);                         \
    barrier_lgkm(); /* B1: r,z published */                                    \
    if (tau == 2) {                                                            \
      const float r = rzb[0][j];                                               \
      const float z = rzb[1][j];                                               \
      const float n = ftanh_((gcur) + r * gh);                                 \
      hj = (1.f - z) * n + z * hj;                                             \
      hsb[j] = hj;                                                             \
      xrow[(tcur) * 64 + j] = hj;                                              \
    }                                                                          \
    barrier_lgkm(); /* B2: h published */                                      \
  }

__global__ __launch_bounds__(256, 2) void scan_kernel(
    float* __restrict__ x, const float* __restrict__ delta_gi,
    const int* __restrict__ idxmap,
    const float* __restrict__ w_ih, const float* __restrict__ w_hh,
    const float* __restrict__ b_ih, const float* __restrict__ b_hh)
{
  const int tid = threadIdx.x;
  const int b = blockIdx.x;
  __shared__ __align__(16) float wsumT[64][192];  // [k][g], 48KB
  __shared__ __align__(16) float xring[16][64];   // 4KB ring
  __shared__ float hsb[64];
  __shared__ float rzb[2][64];
  __shared__ int idxl[512];
  float* xrow = x + (int64_t)b * 32768;

  // One-time staging: wsumT[k][g] = w_ih[g,k] + w_ih[g,64+k]
  for (int i = tid; i < 12288; i += 256) {
    const int k = i >> 7;          // 12288 = 64k * 192g; iterate i = k*192+g
    const int kk = i / 192, gg = i - kk * 192;
    (void)k;
    wsumT[kk][gg] = w_ih[gg * 128 + kk] + w_ih[gg * 128 + 64 + kk];
  }
  for (int i = tid; i < 512; i += 256) idxl[i] = idxmap[b * 512 + i];
  if (tid < 64) hsb[tid] = 0.f;
  if (tid >= 192) {  // DMA wave preloads x[0..7]
    const int lane = tid & 63;
#pragma unroll
    for (int s = 0; s < 8; ++s)
      GLD_LDS4(xrow + s * 64 + lane, &xring[s][0]);
  }
  __syncthreads();  // drains each wave's own vmcnt -> ring slots 0..7 valid

  if (tid < 192) {
    // ---------------- gate wave (tau = r/z/n) ----------------
    const int g = tid;
    const int j = tid & 63;
    const int tau = tid >> 6;
    const float* wc = w_hh + g * 64;
    ALL16(DECL_WC)
    const float bi = b_ih[g];
    const float bc = b_hh[g];
    const float4* hs4 = (const float4*)hsb;
    float hj = 0.f;
    // prologue: gi[0] from ring slot 0
    float g0;
    {
      float s0 = bi, s1 = 0.f, s2 = 0.f, s3 = 0.f;
#pragma unroll
      for (int q = 0; q < 16; ++q) {
        const float4 va = *(const float4*)&xring[0][4 * q];
        s0 += va.x * wsumT[4 * q + 0][g];
        s1 += va.y * wsumT[4 * q + 1][g];
        s2 += va.z * wsumT[4 * q + 2][g];
        s3 += va.w * wsumT[4 * q + 3][g];
      }
      g0 = (s0 + s1) + (s2 + s3);
      const int i0 = idxl[0];
      if (i0 >= 0) g0 += delta_gi[(int64_t)i0 * 192 + g];
    }
    float g1, g2, g3, g4;
    for (int t = 0; t < 512; t += 4) {
      GIBATCH(g1, g2, g3, g4, t)   // gi[t+1..t+4] from ring (landed)
      HSTEP(g0, t)
      HSTEP(g1, t + 1)
      HSTEP(g2, t + 2)
      HSTEP(g3, t + 3)
      g0 = g4;
    }
  } else {
    // ---------------- DMA wave ----------------
    const int lane = tid & 63;
    for (int t = 0; t < 512; ++t) {
      const int tf = (t + 8 < 512) ? (t + 8) : 511;  // always issue exactly 1
      GLD_LDS4(xrow + tf * 64 + lane, &xring[(t + 8) & 15][0]);
      asm volatile("s_waitcnt vmcnt(3)" ::: "memory");  // x[t+5] landed
      barrier_lgkm();  // B1
      barrier_lgkm();  // B2
    }
  }
}

__global__ __launch_bounds__(64) void graphemb_kernel(
    const float* __restrict__ col_sum, float* __restrict__ graph_emb)
{
  const int h = threadIdx.x;
  float s = 0.f;
#pragma unroll 8
  for (int j = 0; j < 512; ++j) s += col_sum[j * 64 + h];
  graph_emb[h] = s * (1.f / 262144.f);
  if (h < 4) graph_emb[64 + h] = 0.f;
}

// One block per (path, direction). 7-step GRU, D=68, gates 204.
__global__ __launch_bounds__(256) void path_kernel(
    const float* __restrict__ x, const int* __restrict__ paths,
    const float* __restrict__ demands, const float* __restrict__ wd,
    const float* __restrict__ graph_emb,
    const float* __restrict__ wih_f, const float* __restrict__ whh_f,
    const float* __restrict__ bih_f, const float* __restrict__ bhh_f,
    const float* __restrict__ wih_b, const float* __restrict__ whh_b,
    const float* __restrict__ bih_b, const float* __restrict__ bhh_b,
    float* __restrict__ h_out)
{
  const int p = blockIdx.x & 63;
  const int dir = blockIdx.x >> 6;
  const int g = threadIdx.x;
  const float* w_ih = dir ? wih_b : wih_f;
  const float* w_hh = dir ? whh_b : whh_f;
  const float* bih = dir ? bih_b : bih_f;
  const float* bhh = dir ? bhh_b : bhh_f;
  __shared__ float feat[7][68], hs[68], rbuf[68], zbuf[68];
  if (g < 68) {
#pragma unroll
    for (int t = 0; t < 7; ++t) {
      const int src = paths[p * 8 + t];
      const int dst = paths[p * 8 + t + 1];
      feat[t][g] = (g < 64) ? x[((int64_t)src * 512 + dst) * 64 + g]
                            : fmaxf(demands[p] * wd[g - 64], 0.f);
    }
    hs[g] = graph_emb[g];
  }
  __syncthreads();
  for (int s = 0; s < 7; ++s) {
    const int t = dir ? (6 - s) : s;
    float acc = 0.f, hacc = 0.f;
    if (g < 204) {
      acc = bih[g];
      hacc = bhh[g];
      for (int k = 0; k < 68; ++k) {
        acc += feat[t][k] * w_ih[g * 68 + k];
        hacc += hs[k] * w_hh[g * 68 + k];
      }
    }
    if (g < 68) rbuf[g] = sig_(acc + hacc);
    else if (g < 136) zbuf[g - 68] = sig_(acc + hacc);
    __syncthreads();
    if (g >= 136 && g < 204) {
      const int j = g - 136;
      const float n = tanhf(acc + rbuf[j] * hacc);
      const float z = zbuf[j];
      const float hn = (1.f - z) * n + z * hs[j];
      hs[j] = hn;
    }
    __syncthreads();
  }
  if (g < 68) h_out[(dir * 64 + p) * 68 + g] = hs[g];
}

__global__ __launch_bounds__(64) void combine_kernel(
    const float* __restrict__ h_out, const float* __restrict__ wq,
    const float* __restrict__ bq, float* __restrict__ out)
{
  const int p = threadIdx.x;
  float l = bq[0];
#pragma unroll
  for (int d = 0; d < 68; ++d)
    l += 0.5f * (h_out[p * 68 + d] + h_out[(64 + p) * 68 + d]) * wq[d];
  float mx = l;
#pragma unroll
  for (int off = 32; off > 0; off >>= 1) mx = fmaxf(mx, __shfl_xor(mx, off, 64));
  const float e = expf(l - mx);
  float s = e;
#pragma unroll
  for (int off = 32; off > 0; off >>= 1) s += __shfl_xor(s, off, 64);
  out[p] = e / s;
}

extern "C" void kernel_launch(void* const* d_in, const int* in_sizes, int n_in,
                              void* d_out, int out_size, void* d_ws, size_t ws_size,
                              hipStream_t stream)
{
  const float* adj = (const float*)d_in[0];
  const int* edges = (const int*)d_in[1];
  const int* paths = (const int*)d_in[2];
  const float* demands = (const float*)d_in[3];
  const float* emb_w = (const float*)d_in[4];
  const float* w1s = (const float*)d_in[5];
  const float* w2s = (const float*)d_in[6];
  const float* w3s = (const float*)d_in[7];
  const float* gru_w_ih = (const float*)d_in[8];
  const float* gru_w_hh = (const float*)d_in[9];
  const float* gru_b_ih = (const float*)d_in[10];
  const float* gru_b_hh = (const float*)d_in[11];
  const float* pf_w_ih = (const float*)d_in[12];
  const float* pf_w_hh = (const float*)d_in[13];
  const float* pf_b_ih = (const float*)d_in[14];
  const float* pf_b_hh = (const float*)d_in[15];
  const float* pb_w_ih = (const float*)d_in[16];
  const float* pb_w_hh = (const float*)d_in[17];
  const float* pb_b_ih = (const float*)d_in[18];
  const float* pb_b_hh = (const float*)d_in[19];
  const float* wq = (const float*)d_in[20];
  const float* bq = (const float*)d_in[21];
  const float* wd = (const float*)d_in[22];
  float* out = (float*)d_out;

  // Workspace layout (floats): ~74.6 MB total (known-safe size)
  float* xA = (float*)d_ws;                    // 512*512*64 = 16777216
  float* col_sum = xA + 16777216;              // 32768
  int* col_nz = (int*)(col_sum + 32768);       // 512
  int* idxmap = col_nz + 512;                  // 262144
  float* delta_gi = (float*)(idxmap + 262144); // 8192*192 = 1572864
  float* graph_emb = delta_gi + 1572864;       // 68 (+pad)
  float* h_out = graph_emb + 128;              // 2*64*68 = 8704

  hipMemsetAsync(idxmap, 0xFF, 262144 * sizeof(int), stream);
  scatter_idx_kernel<<<32, 256, 0, stream>>>(edges, idxmap);
  embed_kernel<<<65536, 256, 0, stream>>>(adj, emb_w, xA);

  for (int t = 0; t < 3; ++t) {
    colsum_kernel<<<512, 256, 0, stream>>>(xA, col_sum, col_nz);
    edge_kernel<<<8192, 64, 0, stream>>>(xA, edges, col_sum, col_nz,
        w1s + t * 4096, w2s + t * 4096, w3s + t * 4096, gru_w_ih, delta_gi);
    scan_kernel<<<512, 256, 0, stream>>>(xA, delta_gi, idxmap,
        gru_w_ih, gru_w_hh, gru_b_ih, gru_b_hh);
  }

  colsum_kernel<<<512, 256, 0, stream>>>(xA, col_sum, col_nz);
  graphemb_kernel<<<1, 64, 0, stream>>>(col_sum, graph_emb);
  path_kernel<<<128, 256, 0, stream>>>(xA, paths, demands, wd, graph_emb,
      pf_w_ih, pf_w_hh, pf_b_ih, pf_b_hh,
      pb_w_ih, pb_w_hh, pb_b_ih, pb_b_hh, h_out);
  combine_kernel<<<1, 64, 0, stream>>>(h_out, wq, bq, out);
}

// Round 12
// 1979.740 us; speedup vs baseline: 2.1384x; 2.1384x over previous
//
#include <hip/hip_runtime.h>

// Sizes (fixed): V=512, F_IN=8, H=64, DH=4, T=3, E=8192, P=64, L=8, D=68

__device__ __forceinline__ float fsig_(float x) { return 1.f / (1.f + __expf(-x)); }
__device__ __forceinline__ float ftanh_(float x) {
  float e = __expf(2.f * x);
  return 1.f - 2.f / (e + 1.f);
}
__device__ __forceinline__ float sig_(float x) { return 1.f / (1.f + expf(-x)); }

// Barrier WITHOUT vmcnt drain: LDS ordering only.
__device__ __forceinline__ void barrier_lgkm() {
  asm volatile("s_waitcnt lgkmcnt(0)\n\ts_barrier" ::: "memory");
}

// Pin a float4 into VGPRs (opaque redefinition, blocks rematerialization).
#define PIN4(v) asm volatile("" : "+v"((v).x), "+v"((v).y), "+v"((v).z), "+v"((v).w))

// async global->LDS, 4 bytes/lane: LDS dst = uniform base + lane*4.
#define GLD_LDS4(gp, lp)                                                       \
  __builtin_amdgcn_global_load_lds(                                            \
      (const __attribute__((address_space(1))) void*)(gp),                     \
      (__attribute__((address_space(3))) void*)(lp), 4, 0, 0)

// NOTE: macro params must NOT collide with float4 member names (x/y/z/w).
#define LD4(p) (*(const float4*)(p))
#define DOT4(acc, va, vb)                                                      \
  do {                                                                         \
    acc += (va).x * (vb).x; acc += (va).y * (vb).y;                            \
    acc += (va).z * (vb).z; acc += (va).w * (vb).w;                            \
  } while (0)

#define ALL16(M) M(0) M(1) M(2) M(3) M(4) M(5) M(6) M(7)                       \
                 M(8) M(9) M(10) M(11) M(12) M(13) M(14) M(15)
#define ALLQ(M) M(0,0) M(1,1) M(2,2) M(3,3) M(4,0) M(5,1) M(6,2) M(7,3)        \
                M(8,0) M(9,1) M(10,2) M(11,3) M(12,0) M(13,1) M(14,2) M(15,3)

// x[i,j,h] = sum_f adj[i,j,f] * emb[h,f]
__global__ __launch_bounds__(256) void embed_kernel(
    const float* __restrict__ adj, const float* __restrict__ emb,
    float* __restrict__ x)
{
  const int64_t row = (int64_t)blockIdx.x * 4 + (threadIdx.x >> 6);
  const int h = threadIdx.x & 63;
  const float* a = adj + row * 8;
  float acc = 0.f;
#pragma unroll
  for (int f = 0; f < 8; ++f) acc += a[f] * emb[h * 8 + f];
  x[row * 64 + h] = acc;
}

// col_sum[j,h] = sum_i x[i,j,h];  col_nz[j] = sum_i sum_h (x[i,j,h]!=0)
__global__ __launch_bounds__(256) void colsum_kernel(
    const float* __restrict__ x, float* __restrict__ col_sum,
    int* __restrict__ col_nz)
{
  const int j = blockIdx.x;
  const int h = threadIdx.x & 63;
  const int w = threadIdx.x >> 6;
  float acc = 0.f;
  int nz = 0;
  for (int i = w; i < 512; i += 4) {
    float v = x[((int64_t)i * 512 + j) * 64 + h];
    acc += v;
    nz += (v != 0.f) ? 1 : 0;
  }
  __shared__ float pacc[4][64];
  __shared__ int pnz[4];
#pragma unroll
  for (int off = 32; off > 0; off >>= 1) nz += __shfl_down(nz, off, 64);
  if (h == 0) pnz[w] = nz;
  pacc[w][h] = acc;
  __syncthreads();
  if (w == 0) {
    col_sum[j * 64 + h] = pacc[0][h] + pacc[1][h] + pacc[2][h] + pacc[3][h];
    if (h == 0) col_nz[j] = pnz[0] + pnz[1] + pnz[2] + pnz[3];
  }
}

__global__ void scatter_idx_kernel(const int* __restrict__ edges,
                                   int* __restrict__ idxmap)
{
  const int e = blockIdx.x * 256 + threadIdx.x;
  if (e < 8192) idxmap[edges[e * 2] * 512 + edges[e * 2 + 1]] = e;
}

// Per-edge message m_e, then delta_gi[e,g] = sum_h (m_e[h]-x_uv[h]) * w_ih[g,h]
__global__ __launch_bounds__(64) void edge_kernel(
    const float* __restrict__ x, const int* __restrict__ edges,
    const float* __restrict__ col_sum, const int* __restrict__ col_nz,
    const float* __restrict__ w1, const float* __restrict__ w2,
    const float* __restrict__ w3, const float* __restrict__ w_ih,
    float* __restrict__ delta_gi)
{
  const int e = blockIdx.x;
  const int h = threadIdx.x;
  const int u = edges[e * 2 + 0];
  const int v = edges[e * 2 + 1];
  __shared__ __align__(16) float xuv[64], ein[64], eout[64], dm[64];
  const float xuvh = x[((int64_t)u * 512 + v) * 64 + h];
  const float xvuh = x[((int64_t)v * 512 + u) * 64 + h];
  xuv[h] = xuvh;
  const int nz_vu = __popcll(__ballot(xvuh != 0.f));
  const int nz_uv = __popcll(__ballot(xuvh != 0.f));
  float n_in = (float)(col_nz[u] - nz_vu) / 64.f;
  if (n_in == 0.f) n_in = 1.f;
  float n_out = (float)(col_nz[v] - nz_uv) / 64.f;
  if (n_out == 0.f) n_out = 1.f;
  ein[h] = (col_sum[u * 64 + h] - xvuh) / n_in;
  eout[h] = (col_sum[v * 64 + h] - xuvh) / n_out;
  __syncthreads();
  const float4* w1r = (const float4*)(w1 + h * 64);
  const float4* w2r = (const float4*)(w2 + h * 64);
  const float4* w3r = (const float4*)(w3 + h * 64);
  const float4* xuv4 = (const float4*)xuv;
  const float4* ein4 = (const float4*)ein;
  const float4* eout4 = (const float4*)eout;
  float acc = 0.f;
#pragma unroll
  for (int kk = 0; kk < 16; ++kk) {
    float4 a = xuv4[kk], b = w1r[kk];
    acc += a.x * b.x + a.y * b.y + a.z * b.z + a.w * b.w;
    a = ein4[kk]; b = w2r[kk];
    acc += a.x * b.x + a.y * b.y + a.z * b.z + a.w * b.w;
    a = eout4[kk]; b = w3r[kk];
    acc += a.x * b.x + a.y * b.y + a.z * b.z + a.w * b.w;
  }
  const float m = fmaxf(acc, 0.f);
  dm[h] = m - xuvh;
  __syncthreads();
  const float4* dm4 = (const float4*)dm;
#pragma unroll
  for (int r = 0; r < 3; ++r) {
    const int gg = h + r * 64;
    const float4* wr = (const float4*)(w_ih + gg * 128);
    float d = 0.f;
#pragma unroll
    for (int kk = 0; kk < 16; ++kk) {
      float4 a = dm4[kk], b = wr[kk];
      d += a.x * b.x + a.y * b.y + a.z * b.z + a.w * b.w;
    }
    delta_gi[e * 192 + gg] = d;
  }
}

// ---- GRU scan v8: no-spill wave split + DMA x-ring. ----
// 384 thr = 6 waves, ONE row per block, grid 512 (2 blocks/CU).
// Waves 0-2 (producers): gate g = wave*64+lane, wsum in 16 pinned f4
//   (64 VGPR). Read x[t+1] from LDS ring (uniform f4 broadcast), write
//   gi into gib dbuf. Wave 0 also DMAs x[t+8] into the ring via
//   global_load_lds + counted s_waitcnt vmcnt(6) (never 0).
// Waves 3-5 (consumers r/z/n): whh class-row in 16 pinned f4 (64 VGPR).
//   Phase A: hacc over h(t-1); r,z -> rzb. B1. Phase B: n-wave only
//   finishes h(t), writes hs + xrow. B2. Every branch <= ~85 VGPR.
#define DECL_W(i)                                                              \
  float4 W##i; {                                                               \
    float4 t0 = LD4(wg + 4 * (i));                                             \
    float4 t1 = LD4(wg + 64 + 4 * (i));                                        \
    W##i.x = t0.x + t1.x; W##i.y = t0.y + t1.y;                                \
    W##i.z = t0.z + t1.z; W##i.w = t0.w + t1.w;                                \
  }                                                                            \
  PIN4(W##i);
#define PX(i, q) { float4 xc = xq4[(i)]; DOT4(a##q, xc, W##i); }
#define DECL_WC(i) float4 WC##i = LD4(wc + 4 * (i)); PIN4(WC##i);
#define HQ(i, q) { float4 hc = hs4[(i)]; DOT4(a##q, hc, WC##i); }

__global__ __launch_bounds__(384, 2) void scan_kernel(
    float* __restrict__ x, const float* __restrict__ delta_gi,
    const int* __restrict__ idxmap,
    const float* __restrict__ w_ih, const float* __restrict__ w_hh,
    const float* __restrict__ b_ih, const float* __restrict__ b_hh)
{
  const int tid = threadIdx.x;
  const int wave = tid >> 6;
  const int lane = tid & 63;
  const int b = blockIdx.x;
  __shared__ __align__(16) float xring[16][64];  // 4KB ring
  __shared__ float gib[2][192];
  __shared__ float rzb[2][64];
  __shared__ __align__(16) float hs[64];
  __shared__ int idxl[512];
  float* xrow = x + (int64_t)b * 32768;

  for (int i = tid; i < 512; i += 384) idxl[i] = idxmap[b * 512 + i];
  if (tid < 64) hs[tid] = 0.f;
  if (wave == 0) {  // preload x[0..7] into ring
#pragma unroll
    for (int s = 0; s < 8; ++s) GLD_LDS4(xrow + s * 64 + lane, &xring[s][0]);
  }
  __syncthreads();  // drains wave0's vmcnt -> slots 0..7 valid; idxl/hs sealed

  if (wave < 3) {
    // ---------------- producer ----------------
    const int g = wave * 64 + lane;
    const float* wg = w_ih + g * 128;
    ALL16(DECL_W)
    const float bi = b_ih[g];
    {  // prologue: gib[0] from ring slot 0
      const float4* xq4 = (const float4*)&xring[0][0];
      float a0 = bi, a1 = 0.f, a2 = 0.f, a3 = 0.f;
      ALLQ(PX)
      float acc = (a0 + a1) + (a2 + a3);
      const int i0 = idxl[0];
      const float d0 = delta_gi[(int64_t)(i0 < 0 ? 0 : i0) * 192 + g];
      acc += (i0 >= 0) ? d0 : 0.f;
      gib[0][g] = acc;
    }
    const int i1 = idxl[1];
    float dg_cur = delta_gi[(int64_t)(i1 < 0 ? 0 : i1) * 192 + g];
    dg_cur = (i1 >= 0) ? dg_cur : 0.f;
    barrier_lgkm();  // P: gib[0] published
    for (int t = 0; t < 512; ++t) {
      // Phase A: gi[t+1] (slot write harmless at t=511)
      const float4* xq4 = (const float4*)&xring[(t + 1) & 15][0];
      float a0 = bi + dg_cur, a1 = 0.f, a2 = 0.f, a3 = 0.f;
      ALLQ(PX)
      gib[(t + 1) & 1][g] = (a0 + a1) + (a2 + a3);
      const int t2 = (t + 2 < 512) ? t + 2 : 511;
      const int idn = idxl[t2];
      float dgt = delta_gi[(int64_t)(idn < 0 ? 0 : idn) * 192 + g];
      dgt = (idn >= 0) ? dgt : 0.f;
      if (wave == 0) {
        const int tf = (t + 8 < 512) ? t + 8 : 511;
        GLD_LDS4(xrow + tf * 64 + lane, &xring[(t + 8) & 15][0]);
        asm volatile("s_waitcnt vmcnt(6)" ::: "memory");
      }
      barrier_lgkm();  // B1
      barrier_lgkm();  // B2
      dg_cur = dgt;
    }
  } else if (wave < 5) {
    // ---------------- consumer r (wave 3) / z (wave 4) ----------------
    const int cls = wave - 3;
    const int j = lane;
    const float* wc = w_hh + (cls * 64 + j) * 64;
    ALL16(DECL_WC)
    const float bc = b_hh[cls * 64 + j];
    __builtin_amdgcn_s_setprio(1);
    barrier_lgkm();  // P
    const float4* hs4 = (const float4*)hs;
    for (int t = 0; t < 512; ++t) {
      const float gc = gib[t & 1][cls * 64 + j];
      float a0 = bc, a1 = 0.f, a2 = 0.f, a3 = 0.f;
      ALLQ(HQ)
      rzb[cls][j] = fsig_(gc + (a0 + a1) + (a2 + a3));
      barrier_lgkm();  // B1
      barrier_lgkm();  // B2
    }
  } else {
    // ---------------- consumer n (wave 5) ----------------
    const int j = lane;
    const float* wc = w_hh + (128 + j) * 64;
    ALL16(DECL_WC)
    const float bc = b_hh[128 + j];
    float hj = 0.f;
    __builtin_amdgcn_s_setprio(1);
    barrier_lgkm();  // P
    const float4* hs4 = (const float4*)hs;
    for (int t = 0; t < 512; ++t) {
      const float gn = gib[t & 1][128 + j];
      float a0 = bc, a1 = 0.f, a2 = 0.f, a3 = 0.f;
      ALLQ(HQ)
      const float nacc = (a0 + a1) + (a2 + a3);
      barrier_lgkm();  // B1: r,z published
      const float r = rzb[0][j];
      const float z = rzb[1][j];
      const float nn = ftanh_(gn + r * nacc);
      hj = (1.f - z) * nn + z * hj;
      hs[j] = hj;
      xrow[t * 64 + j] = hj;
      barrier_lgkm();  // B2: h published
    }
  }
}

__global__ __launch_bounds__(64) void graphemb_kernel(
    const float* __restrict__ col_sum, float* __restrict__ graph_emb)
{
  const int h = threadIdx.x;
  float s = 0.f;
#pragma unroll 8
  for (int j = 0; j < 512; ++j) s += col_sum[j * 64 + h];
  graph_emb[h] = s * (1.f / 262144.f);
  if (h < 4) graph_emb[64 + h] = 0.f;
}

// One block per (path, direction). 7-step GRU, D=68, gates 204.
__global__ __launch_bounds__(256) void path_kernel(
    const float* __restrict__ x, const int* __restrict__ paths,
    const float* __restrict__ demands, const float* __restrict__ wd,
    const float* __restrict__ graph_emb,
    const float* __restrict__ wih_f, const float* __restrict__ whh_f,
    const float* __restrict__ bih_f, const float* __restrict__ bhh_f,
    const float* __restrict__ wih_b, const float* __restrict__ whh_b,
    const float* __restrict__ bih_b, const float* __restrict__ bhh_b,
    float* __restrict__ h_out)
{
  const int p = blockIdx.x & 63;
  const int dir = blockIdx.x >> 6;
  const int g = threadIdx.x;
  const float* w_ih = dir ? wih_b : wih_f;
  const float* w_hh = dir ? whh_b : whh_f;
  const float* bih = dir ? bih_b : bih_f;
  const float* bhh = dir ? bhh_b : bhh_f;
  __shared__ float feat[7][68], hs[68], rbuf[68], zbuf[68];
  if (g < 68) {
#pragma unroll
    for (int t = 0; t < 7; ++t) {
      const int src = paths[p * 8 + t];
      const int dst = paths[p * 8 + t + 1];
      feat[t][g] = (g < 64) ? x[((int64_t)src * 512 + dst) * 64 + g]
                            : fmaxf(demands[p] * wd[g - 64], 0.f);
    }
    hs[g] = graph_emb[g];
  }
  __syncthreads();
  for (int s = 0; s < 7; ++s) {
    const int t = dir ? (6 - s) : s;
    float acc = 0.f, hacc = 0.f;
    if (g < 204) {
      acc = bih[g];
      hacc = bhh[g];
      for (int k = 0; k < 68; ++k) {
        acc += feat[t][k] * w_ih[g * 68 + k];
        hacc += hs[k] * w_hh[g * 68 + k];
      }
    }
    if (g < 68) rbuf[g] = sig_(acc + hacc);
    else if (g < 136) zbuf[g - 68] = sig_(acc + hacc);
    __syncthreads();
    if (g >= 136 && g < 204) {
      const int j = g - 136;
      const float n = tanhf(acc + rbuf[j] * hacc);
      const float z = zbuf[j];
      const float hn = (1.f - z) * n + z * hs[j];
      hs[j] = hn;
    }
    __syncthreads();
  }
  if (g < 68) h_out[(dir * 64 + p) * 68 + g] = hs[g];
}

__global__ __launch_bounds__(64) void combine_kernel(
    const float* __restrict__ h_out, const float* __restrict__ wq,
    const float* __restrict__ bq, float* __restrict__ out)
{
  const int p = threadIdx.x;
  float l = bq[0];
#pragma unroll
  for (int d = 0; d < 68; ++d)
    l += 0.5f * (h_out[p * 68 + d] + h_out[(64 + p) * 68 + d]) * wq[d];
  float mx = l;
#pragma unroll
  for (int off = 32; off > 0; off >>= 1) mx = fmaxf(mx, __shfl_xor(mx, off, 64));
  const float e = expf(l - mx);
  float s = e;
#pragma unroll
  for (int off = 32; off > 0; off >>= 1) s += __shfl_xor(s, off, 64);
  out[p] = e / s;
}

extern "C" void kernel_launch(void* const* d_in, const int* in_sizes, int n_in,
                              void* d_out, int out_size, void* d_ws, size_t ws_size,
                              hipStream_t stream)
{
  const float* adj = (const float*)d_in[0];
  const int* edges = (const int*)d_in[1];
  const int* paths = (const int*)d_in[2];
  const float* demands = (const float*)d_in[3];
  const float* emb_w = (const float*)d_in[4];
  const float* w1s = (const float*)d_in[5];
  const float* w2s = (const float*)d_in[6];
  const float* w3s = (const float*)d_in[7];
  const float* gru_w_ih = (const float*)d_in[8];
  const float* gru_w_hh = (const float*)d_in[9];
  const float* gru_b_ih = (const float*)d_in[10];
  const float* gru_b_hh = (const float*)d_in[11];
  const float* pf_w_ih = (const float*)d_in[12];
  const float* pf_w_hh = (const float*)d_in[13];
  const float* pf_b_ih = (const float*)d_in[14];
  const float* pf_b_hh = (const float*)d_in[15];
  const float* pb_w_ih = (const float*)d_in[16];
  const float* pb_w_hh = (const float*)d_in[17];
  const float* pb_b_ih = (const float*)d_in[18];
  const float* pb_b_hh = (const float*)d_in[19];
  const float* wq = (const float*)d_in[20];
  const float* bq = (const float*)d_in[21];
  const float* wd = (const float*)d_in[22];
  float* out = (float*)d_out;

  // Workspace layout (floats): ~74.6 MB total (known-safe size)
  float* xA = (float*)d_ws;                    // 512*512*64 = 16777216
  float* col_sum = xA + 16777216;              // 32768
  int* col_nz = (int*)(col_sum + 32768);       // 512
  int* idxmap = col_nz + 512;                  // 262144
  float* delta_gi = (float*)(idxmap + 262144); // 8192*192 = 1572864
  float* graph_emb = delta_gi + 1572864;       // 68 (+pad)
  float* h_out = graph_emb + 128;              // 2*64*68 = 8704

  hipMemsetAsync(idxmap, 0xFF, 262144 * sizeof(int), stream);
  scatter_idx_kernel<<<32, 256, 0, stream>>>(edges, idxmap);
  embed_kernel<<<65536, 256, 0, stream>>>(adj, emb_w, xA);

  for (int t = 0; t < 3; ++t) {
    colsum_kernel<<<512, 256, 0, stream>>>(xA, col_sum, col_nz);
    edge_kernel<<<8192, 64, 0, stream>>>(xA, edges, col_sum, col_nz,
        w1s + t * 4096, w2s + t * 4096, w3s + t * 4096, gru_w_ih, delta_gi);
    scan_kernel<<<512, 384, 0, stream>>>(xA, delta_gi, idxmap,
        gru_w_ih, gru_w_hh, gru_b_ih, gru_b_hh);
  }

  colsum_kernel<<<512, 256, 0, stream>>>(xA, col_sum, col_nz);
  graphemb_kernel<<<1, 64, 0, stream>>>(col_sum, graph_emb);
  path_kernel<<<128, 256, 0, stream>>>(xA, paths, demands, wd, graph_emb,
      pf_w_ih, pf_w_hh, pf_b_ih, pf_b_hh,
      pb_w_ih, pb_w_hh, pb_b_ih, pb_b_hh, h_out);
  combine_kernel<<<1, 64, 0, stream>>>(h_out, wq, bq, out);
}

// Round 13
// 1961.697 us; speedup vs baseline: 2.1581x; 1.0092x over previous
//
#include <hip/hip_runtime.h>

// Sizes (fixed): V=512, F_IN=8, H=64, DH=4, T=3, E=8192, P=64, L=8, D=68

__device__ __forceinline__ float fsig_(float x) { return 1.f / (1.f + __expf(-x)); }
__device__ __forceinline__ float ftanh_(float x) {
  float e = __expf(2.f * x);
  return 1.f - 2.f / (e + 1.f);
}
__device__ __forceinline__ float sig_(float x) { return 1.f / (1.f + expf(-x)); }

// Barrier WITHOUT vmcnt drain: LDS ordering only.
__device__ __forceinline__ void barrier_lgkm() {
  asm volatile("s_waitcnt lgkmcnt(0)\n\ts_barrier" ::: "memory");
}

// Pin a float4 into VGPRs (opaque redefinition, blocks rematerialization).
// MUST be re-applied INSIDE the loop: applied once outside, LLVM still
// re-loads the value from global memory each iteration (r12: VGPR=56 proved
// the weights were never resident).
#define PIN4(v) asm volatile("" : "+v"((v).x), "+v"((v).y), "+v"((v).z), "+v"((v).w))

// async global->LDS, 4 bytes/lane: LDS dst = uniform base + lane*4.
#define GLD_LDS4(gp, lp)                                                       \
  __builtin_amdgcn_global_load_lds(                                            \
      (const __attribute__((address_space(1))) void*)(gp),                     \
      (__attribute__((address_space(3))) void*)(lp), 4, 0, 0)

// NOTE: macro params must NOT collide with float4 member names (x/y/z/w).
#define LD4(p) (*(const float4*)(p))
#define DOT4(acc, va, vb)                                                      \
  do {                                                                         \
    acc += (va).x * (vb).x; acc += (va).y * (vb).y;                            \
    acc += (va).z * (vb).z; acc += (va).w * (vb).w;                            \
  } while (0)

#define ALL16(M) M(0) M(1) M(2) M(3) M(4) M(5) M(6) M(7)                       \
                 M(8) M(9) M(10) M(11) M(12) M(13) M(14) M(15)
#define ALLQ(M) M(0,0) M(1,1) M(2,2) M(3,3) M(4,0) M(5,1) M(6,2) M(7,3)        \
                M(8,0) M(9,1) M(10,2) M(11,3) M(12,0) M(13,1) M(14,2) M(15,3)

// x[i,j,h] = sum_f adj[i,j,f] * emb[h,f]
__global__ __launch_bounds__(256) void embed_kernel(
    const float* __restrict__ adj, const float* __restrict__ emb,
    float* __restrict__ x)
{
  const int64_t row = (int64_t)blockIdx.x * 4 + (threadIdx.x >> 6);
  const int h = threadIdx.x & 63;
  const float* a = adj + row * 8;
  float acc = 0.f;
#pragma unroll
  for (int f = 0; f < 8; ++f) acc += a[f] * emb[h * 8 + f];
  x[row * 64 + h] = acc;
}

// col_sum[j,h] = sum_i x[i,j,h];  col_nz[j] = sum_i sum_h (x[i,j,h]!=0)
__global__ __launch_bounds__(256) void colsum_kernel(
    const float* __restrict__ x, float* __restrict__ col_sum,
    int* __restrict__ col_nz)
{
  const int j = blockIdx.x;
  const int h = threadIdx.x & 63;
  const int w = threadIdx.x >> 6;
  float acc = 0.f;
  int nz = 0;
  for (int i = w; i < 512; i += 4) {
    float v = x[((int64_t)i * 512 + j) * 64 + h];
    acc += v;
    nz += (v != 0.f) ? 1 : 0;
  }
  __shared__ float pacc[4][64];
  __shared__ int pnz[4];
#pragma unroll
  for (int off = 32; off > 0; off >>= 1) nz += __shfl_down(nz, off, 64);
  if (h == 0) pnz[w] = nz;
  pacc[w][h] = acc;
  __syncthreads();
  if (w == 0) {
    col_sum[j * 64 + h] = pacc[0][h] + pacc[1][h] + pacc[2][h] + pacc[3][h];
    if (h == 0) col_nz[j] = pnz[0] + pnz[1] + pnz[2] + pnz[3];
  }
}

__global__ void scatter_idx_kernel(const int* __restrict__ edges,
                                   int* __restrict__ idxmap)
{
  const int e = blockIdx.x * 256 + threadIdx.x;
  if (e < 8192) idxmap[edges[e * 2] * 512 + edges[e * 2 + 1]] = e;
}

// Per-edge message m_e, then delta_gi[e,g] = sum_h (m_e[h]-x_uv[h]) * w_ih[g,h]
__global__ __launch_bounds__(64) void edge_kernel(
    const float* __restrict__ x, const int* __restrict__ edges,
    const float* __restrict__ col_sum, const int* __restrict__ col_nz,
    const float* __restrict__ w1, const float* __restrict__ w2,
    const float* __restrict__ w3, const float* __restrict__ w_ih,
    float* __restrict__ delta_gi)
{
  const int e = blockIdx.x;
  const int h = threadIdx.x;
  const int u = edges[e * 2 + 0];
  const int v = edges[e * 2 + 1];
  __shared__ __align__(16) float xuv[64], ein[64], eout[64], dm[64];
  const float xuvh = x[((int64_t)u * 512 + v) * 64 + h];
  const float xvuh = x[((int64_t)v * 512 + u) * 64 + h];
  xuv[h] = xuvh;
  const int nz_vu = __popcll(__ballot(xvuh != 0.f));
  const int nz_uv = __popcll(__ballot(xuvh != 0.f));
  float n_in = (float)(col_nz[u] - nz_vu) / 64.f;
  if (n_in == 0.f) n_in = 1.f;
  float n_out = (float)(col_nz[v] - nz_uv) / 64.f;
  if (n_out == 0.f) n_out = 1.f;
  ein[h] = (col_sum[u * 64 + h] - xvuh) / n_in;
  eout[h] = (col_sum[v * 64 + h] - xuvh) / n_out;
  __syncthreads();
  const float4* w1r = (const float4*)(w1 + h * 64);
  const float4* w2r = (const float4*)(w2 + h * 64);
  const float4* w3r = (const float4*)(w3 + h * 64);
  const float4* xuv4 = (const float4*)xuv;
  const float4* ein4 = (const float4*)ein;
  const float4* eout4 = (const float4*)eout;
  float acc = 0.f;
#pragma unroll
  for (int kk = 0; kk < 16; ++kk) {
    float4 a = xuv4[kk], b = w1r[kk];
    acc += a.x * b.x + a.y * b.y + a.z * b.z + a.w * b.w;
    a = ein4[kk]; b = w2r[kk];
    acc += a.x * b.x + a.y * b.y + a.z * b.z + a.w * b.w;
    a = eout4[kk]; b = w3r[kk];
    acc += a.x * b.x + a.y * b.y + a.z * b.z + a.w * b.w;
  }
  const float m = fmaxf(acc, 0.f);
  dm[h] = m - xuvh;
  __syncthreads();
  const float4* dm4 = (const float4*)dm;
#pragma unroll
  for (int r = 0; r < 3; ++r) {
    const int gg = h + r * 64;
    const float4* wr = (const float4*)(w_ih + gg * 128);
    float d = 0.f;
#pragma unroll
    for (int kk = 0; kk < 16; ++kk) {
      float4 a = dm4[kk], b = wr[kk];
      d += a.x * b.x + a.y * b.y + a.z * b.z + a.w * b.w;
    }
    delta_gi[e * 192 + gg] = d;
  }
}

// ---- GRU scan v9: v8 + weights pinned INSIDE the loop. ----
// 384 thr = 6 waves, ONE row per block, grid 512 (2 blocks/CU).
// Waves 0-2 (producers): gate g = wave*64+lane, wsum in 16 float4 — re-pinned
//   every iteration so LLVM cannot serve them by per-step L2 reloads.
//   Wave 0 also DMAs x[t+8] into the ring (counted vmcnt, never 0).
// Waves 3-5 (consumers r/z/n): whh class-row in 16 float4, re-pinned every
//   iteration. 2 lgkm-only barriers per step.
#define DECL_W(i)                                                              \
  float4 W##i; {                                                               \
    float4 t0 = LD4(wg + 4 * (i));                                             \
    float4 t1 = LD4(wg + 64 + 4 * (i));                                        \
    W##i.x = t0.x + t1.x; W##i.y = t0.y + t1.y;                                \
    W##i.z = t0.z + t1.z; W##i.w = t0.w + t1.w;                                \
  }                                                                            \
  PIN4(W##i);
#define RPW(i) PIN4(W##i);
#define PX(i, q) { float4 xc = xq4[(i)]; DOT4(a##q, xc, W##i); }
#define DECL_WC(i) float4 WC##i = LD4(wc + 4 * (i)); PIN4(WC##i);
#define RPC(i) PIN4(WC##i);
#define HQ(i, q) { float4 hc = hs4[(i)]; DOT4(a##q, hc, WC##i); }

__global__ __launch_bounds__(384, 2) void scan_kernel(
    float* __restrict__ x, const float* __restrict__ delta_gi,
    const int* __restrict__ idxmap,
    const float* __restrict__ w_ih, const float* __restrict__ w_hh,
    const float* __restrict__ b_ih, const float* __restrict__ b_hh)
{
  const int tid = threadIdx.x;
  const int wave = tid >> 6;
  const int lane = tid & 63;
  const int b = blockIdx.x;
  __shared__ __align__(16) float xring[16][64];  // 4KB ring
  __shared__ float gib[2][192];
  __shared__ float rzb[2][64];
  __shared__ __align__(16) float hs[64];
  __shared__ int idxl[512];
  float* xrow = x + (int64_t)b * 32768;

  for (int i = tid; i < 512; i += 384) idxl[i] = idxmap[b * 512 + i];
  if (tid < 64) hs[tid] = 0.f;
  if (wave == 0) {  // preload x[0..7] into ring
#pragma unroll
    for (int s = 0; s < 8; ++s) GLD_LDS4(xrow + s * 64 + lane, &xring[s][0]);
  }
  __syncthreads();  // drains wave0's vmcnt -> slots 0..7 valid; idxl/hs sealed

  if (wave < 3) {
    // ---------------- producer ----------------
    const int g = wave * 64 + lane;
    const float* wg = w_ih + g * 128;
    ALL16(DECL_W)
    const float bi = b_ih[g];
    {  // prologue: gib[0] from ring slot 0
      const float4* xq4 = (const float4*)&xring[0][0];
      float a0 = bi, a1 = 0.f, a2 = 0.f, a3 = 0.f;
      ALLQ(PX)
      float acc = (a0 + a1) + (a2 + a3);
      const int i0 = idxl[0];
      const float d0 = delta_gi[(int64_t)(i0 < 0 ? 0 : i0) * 192 + g];
      acc += (i0 >= 0) ? d0 : 0.f;
      gib[0][g] = acc;
    }
    const int i1 = idxl[1];
    float dg_cur = delta_gi[(int64_t)(i1 < 0 ? 0 : i1) * 192 + g];
    dg_cur = (i1 >= 0) ? dg_cur : 0.f;
    barrier_lgkm();  // P: gib[0] published
    for (int t = 0; t < 512; ++t) {
      ALL16(RPW)  // re-pin: forces weights to stay register-resident
      // Phase A: gi[t+1] (slot write harmless at t=511)
      const float4* xq4 = (const float4*)&xring[(t + 1) & 15][0];
      float a0 = bi + dg_cur, a1 = 0.f, a2 = 0.f, a3 = 0.f;
      ALLQ(PX)
      gib[(t + 1) & 1][g] = (a0 + a1) + (a2 + a3);
      const int t2 = (t + 2 < 512) ? t + 2 : 511;
      const int idn = idxl[t2];
      float dgt = delta_gi[(int64_t)(idn < 0 ? 0 : idn) * 192 + g];
      dgt = (idn >= 0) ? dgt : 0.f;
      if (wave == 0) {
        const int tf = (t + 8 < 512) ? t + 8 : 511;
        GLD_LDS4(xrow + tf * 64 + lane, &xring[(t + 8) & 15][0]);
        asm volatile("s_waitcnt vmcnt(6)" ::: "memory");
      }
      barrier_lgkm();  // B1
      barrier_lgkm();  // B2
      dg_cur = dgt;
    }
  } else if (wave < 5) {
    // ---------------- consumer r (wave 3) / z (wave 4) ----------------
    const int cls = wave - 3;
    const int j = lane;
    const float* wc = w_hh + (cls * 64 + j) * 64;
    ALL16(DECL_WC)
    const float bc = b_hh[cls * 64 + j];
    __builtin_amdgcn_s_setprio(1);
    barrier_lgkm();  // P
    const float4* hs4 = (const float4*)hs;
    for (int t = 0; t < 512; ++t) {
      ALL16(RPC)  // re-pin
      const float gc = gib[t & 1][cls * 64 + j];
      float a0 = bc, a1 = 0.f, a2 = 0.f, a3 = 0.f;
      ALLQ(HQ)
      rzb[cls][j] = fsig_(gc + (a0 + a1) + (a2 + a3));
      barrier_lgkm();  // B1
      barrier_lgkm();  // B2
    }
  } else {
    // ---------------- consumer n (wave 5) ----------------
    const int j = lane;
    const float* wc = w_hh + (128 + j) * 64;
    ALL16(DECL_WC)
    const float bc = b_hh[128 + j];
    float hj = 0.f;
    __builtin_amdgcn_s_setprio(1);
    barrier_lgkm();  // P
    const float4* hs4 = (const float4*)hs;
    for (int t = 0; t < 512; ++t) {
      ALL16(RPC)  // re-pin
      const float gn = gib[t & 1][128 + j];
      float a0 = bc, a1 = 0.f, a2 = 0.f, a3 = 0.f;
      ALLQ(HQ)
      const float nacc = (a0 + a1) + (a2 + a3);
      barrier_lgkm();  // B1: r,z published
      const float r = rzb[0][j];
      const float z = rzb[1][j];
      const float nn = ftanh_(gn + r * nacc);
      hj = (1.f - z) * nn + z * hj;
      hs[j] = hj;
      xrow[t * 64 + j] = hj;
      barrier_lgkm();  // B2: h published
    }
  }
}

__global__ __launch_bounds__(64) void graphemb_kernel(
    const float* __restrict__ col_sum, float* __restrict__ graph_emb)
{
  const int h = threadIdx.x;
  float s = 0.f;
#pragma unroll 8
  for (int j = 0; j < 512; ++j) s += col_sum[j * 64 + h];
  graph_emb[h] = s * (1.f / 262144.f);
  if (h < 4) graph_emb[64 + h] = 0.f;
}

// One block per (path, direction). 7-step GRU, D=68, gates 204.
__global__ __launch_bounds__(256) void path_kernel(
    const float* __restrict__ x, const int* __restrict__ paths,
    const float* __restrict__ demands, const float* __restrict__ wd,
    const float* __restrict__ graph_emb,
    const float* __restrict__ wih_f, const float* __restrict__ whh_f,
    const float* __restrict__ bih_f, const float* __restrict__ bhh_f,
    const float* __restrict__ wih_b, const float* __restrict__ whh_b,
    const float* __restrict__ bih_b, const float* __restrict__ bhh_b,
    float* __restrict__ h_out)
{
  const int p = blockIdx.x & 63;
  const int dir = blockIdx.x >> 6;
  const int g = threadIdx.x;
  const float* w_ih = dir ? wih_b : wih_f;
  const float* w_hh = dir ? whh_b : whh_f;
  const float* bih = dir ? bih_b : bih_f;
  const float* bhh = dir ? bhh_b : bhh_f;
  __shared__ float feat[7][68], hs[68], rbuf[68], zbuf[68];
  if (g < 68) {
#pragma unroll
    for (int t = 0; t < 7; ++t) {
      const int src = paths[p * 8 + t];
      const int dst = paths[p * 8 + t + 1];
      feat[t][g] = (g < 64) ? x[((int64_t)src * 512 + dst) * 64 + g]
                            : fmaxf(demands[p] * wd[g - 64], 0.f);
    }
    hs[g] = graph_emb[g];
  }
  __syncthreads();
  for (int s = 0; s < 7; ++s) {
    const int t = dir ? (6 - s) : s;
    float acc = 0.f, hacc = 0.f;
    if (g < 204) {
      acc = bih[g];
      hacc = bhh[g];
      for (int k = 0; k < 68; ++k) {
        acc += feat[t][k] * w_ih[g * 68 + k];
        hacc += hs[k] * w_hh[g * 68 + k];
      }
    }
    if (g < 68) rbuf[g] = sig_(acc + hacc);
    else if (g < 136) zbuf[g - 68] = sig_(acc + hacc);
    __syncthreads();
    if (g >= 136 && g < 204) {
      const int j = g - 136;
      const float n = tanhf(acc + rbuf[j] * hacc);
      const float z = zbuf[j];
      const float hn = (1.f - z) * n + z * hs[j];
      hs[j] = hn;
    }
    __syncthreads();
  }
  if (g < 68) h_out[(dir * 64 + p) * 68 + g] = hs[g];
}

__global__ __launch_bounds__(64) void combine_kernel(
    const float* __restrict__ h_out, const float* __restrict__ wq,
    const float* __restrict__ bq, float* __restrict__ out)
{
  const int p = threadIdx.x;
  float l = bq[0];
#pragma unroll
  for (int d = 0; d < 68; ++d)
    l += 0.5f * (h_out[p * 68 + d] + h_out[(64 + p) * 68 + d]) * wq[d];
  float mx = l;
#pragma unroll
  for (int off = 32; off > 0; off >>= 1) mx = fmaxf(mx, __shfl_xor(mx, off, 64));
  const float e = expf(l - mx);
  float s = e;
#pragma unroll
  for (int off = 32; off > 0; off >>= 1) s += __shfl_xor(s, off, 64);
  out[p] = e / s;
}

extern "C" void kernel_launch(void* const* d_in, const int* in_sizes, int n_in,
                              void* d_out, int out_size, void* d_ws, size_t ws_size,
                              hipStream_t stream)
{
  const float* adj = (const float*)d_in[0];
  const int* edges = (const int*)d_in[1];
  const int* paths = (const int*)d_in[2];
  const float* demands = (const float*)d_in[3];
  const float* emb_w = (const float*)d_in[4];
  const float* w1s = (const float*)d_in[5];
  const float* w2s = (const float*)d_in[6];
  const float* w3s = (const float*)d_in[7];
  const float* gru_w_ih = (const float*)d_in[8];
  const float* gru_w_hh = (const float*)d_in[9];
  const float* gru_b_ih = (const float*)d_in[10];
  const float* gru_b_hh = (const float*)d_in[11];
  const float* pf_w_ih = (const float*)d_in[12];
  const float* pf_w_hh = (const float*)d_in[13];
  const float* pf_b_ih = (const float*)d_in[14];
  const float* pf_b_hh = (const float*)d_in[15];
  const float* pb_w_ih = (const float*)d_in[16];
  const float* pb_w_hh = (const float*)d_in[17];
  const float* pb_b_ih = (const float*)d_in[18];
  const float* pb_b_hh = (const float*)d_in[19];
  const float* wq = (const float*)d_in[20];
  const float* bq = (const float*)d_in[21];
  const float* wd = (const float*)d_in[22];
  float* out = (float*)d_out;

  // Workspace layout (floats): ~74.6 MB total (known-safe size)
  float* xA = (float*)d_ws;                    // 512*512*64 = 16777216
  float* col_sum = xA + 16777216;              // 32768
  int* col_nz = (int*)(col_sum + 32768);       // 512
  int* idxmap = col_nz + 512;                  // 262144
  float* delta_gi = (float*)(idxmap + 262144); // 8192*192 = 1572864
  float* graph_emb = delta_gi + 1572864;       // 68 (+pad)
  float* h_out = graph_emb + 128;              // 2*64*68 = 8704

  hipMemsetAsync(idxmap, 0xFF, 262144 * sizeof(int), stream);
  scatter_idx_kernel<<<32, 256, 0, stream>>>(edges, idxmap);
  embed_kernel<<<65536, 256, 0, stream>>>(adj, emb_w, xA);

  for (int t = 0; t < 3; ++t) {
    colsum_kernel<<<512, 256, 0, stream>>>(xA, col_sum, col_nz);
    edge_kernel<<<8192, 64, 0, stream>>>(xA, edges, col_sum, col_nz,
        w1s + t * 4096, w2s + t * 4096, w3s + t * 4096, gru_w_ih, delta_gi);
    scan_kernel<<<512, 384, 0, stream>>>(xA, delta_gi, idxmap,
        gru_w_ih, gru_w_hh, gru_b_ih, gru_b_hh);
  }

  colsum_kernel<<<512, 256, 0, stream>>>(xA, col_sum, col_nz);
  graphemb_kernel<<<1, 64, 0, stream>>>(col_sum, graph_emb);
  path_kernel<<<128, 256, 0, stream>>>(xA, paths, demands, wd, graph_emb,
      pf_w_ih, pf_w_hh, pf_b_ih, pf_b_hh,
      pb_w_ih, pb_w_hh, pb_b_ih, pb_b_hh, h_out);
  combine_kernel<<<1, 64, 0, stream>>>(h_out, wq, bq, out);
}